// Round 9
// baseline (184.991 us; speedup 1.0000x reference)
//
#include <hip/hip_runtime.h>

#define BATCH 8
#define NN 10000      // nodes per graph (N)
#define STB 1024      // scatter block size (16 waves)

typedef _Float16 h2 __attribute__((ext_vector_type(2)));

// Packed 2xf16 LDS atomic add (ds_pk_add_f16): one atomic covers TWO batches.
__device__ __forceinline__ void lds_pk_add(h2* p, h2 v) {
    __builtin_amdgcn_ds_atomic_fadd_v2f16(
        (__attribute__((address_space(3))) h2*)p, v);
}

// ---------------- scatter phase 1 ----------------
// block = (chunk k, batch-pair bp). Stage fx = tanh(values) for batches
// (2bp, 2bp+1) as packed f16; accumulate msg = w * fx into h2 LDS accumulator
// with ds_pk_add_f16. partial layout: partial[(k*4+bp)*N + t]  (h2)
__global__ __launch_bounds__(STB, 8) void scatter1_kernel(
        const float* __restrict__ values,
        const float* __restrict__ w,
        const int* __restrict__ idx,
        h2* __restrict__ partial,
        int E, int N, int chunk)
{
    __shared__ alignas(16) h2 acc2[NN];
    __shared__ alignas(16) h2 fxs2[NN];
    const int k = blockIdx.x, bp = blockIdx.y;
    const float* __restrict__ v0 = values + (long)(2 * bp) * N;
    const float* __restrict__ v1 = v0 + N;

    int n4 = N >> 2;                       // N%4==0
    int4* az = (int4*)acc2;
    for (int i = threadIdx.x; i < n4; i += STB) az[i] = make_int4(0, 0, 0, 0);
    for (int i = threadIdx.x; i < N; i += STB) {
        h2 f = { (_Float16)tanhf(v0[i]), (_Float16)tanhf(v1[i]) };
        fxs2[i] = f;
    }
    __syncthreads();

    long e0 = (long)k * chunk, e1 = e0 + chunk;
    if (e1 > E) e1 = E;
    long n = e1 - e0, nv = n >> 2;
    const int4*   g4p = (const int4*)(idx + e0);           // src row 0: gather
    const int4*   s4p = (const int4*)(idx + (long)E + e0); // tgt row 1: scatter
    const float4* w4p = (const float4*)(w + e0);

    for (long v = threadIdx.x; v < nv; v += STB) {
        int4 gi = g4p[v]; int4 si = s4p[v]; float4 wv = w4p[v];
        h2 w0 = { (_Float16)wv.x, (_Float16)wv.x };
        h2 w1 = { (_Float16)wv.y, (_Float16)wv.y };
        h2 w2 = { (_Float16)wv.z, (_Float16)wv.z };
        h2 w3 = { (_Float16)wv.w, (_Float16)wv.w };
        h2 m0 = w0 * fxs2[gi.x];
        h2 m1 = w1 * fxs2[gi.y];
        h2 m2 = w2 * fxs2[gi.z];
        h2 m3 = w3 * fxs2[gi.w];
        lds_pk_add(&acc2[si.x], m0);
        lds_pk_add(&acc2[si.y], m1);
        lds_pk_add(&acc2[si.z], m2);
        lds_pk_add(&acc2[si.w], m3);
    }
    for (long e = (nv << 2) + threadIdx.x; e < n; e += STB) {
        int gi = idx[e0 + e], si = idx[(long)E + e0 + e];
        _Float16 wf = (_Float16)w[e0 + e];
        h2 wb = { wf, wf };
        lds_pk_add(&acc2[si], wb * fxs2[gi]);
    }
    __syncthreads();

    int4* pz = (int4*)(partial + ((long)k * 4 + bp) * N);
    for (int i = threadIdx.x; i < n4; i += STB) pz[i] = az[i];
}

// ---------------- scatter phase 2 ----------------
// gather err at tgt, scatter to src. err staged from packed err2.
__global__ __launch_bounds__(STB, 8) void scatter2_kernel(
        const h2* __restrict__ err2,   // [4][N] h2 (per batch-pair)
        const float* __restrict__ w,
        const int* __restrict__ idx,
        h2* __restrict__ partial,
        int E, int N, int chunk)
{
    __shared__ alignas(16) h2 acc2[NN];
    __shared__ alignas(16) h2 es2[NN];
    const int k = blockIdx.x, bp = blockIdx.y;

    int n4 = N >> 2;
    int4* az = (int4*)acc2;
    int4* ez = (int4*)es2;
    const int4* e4 = (const int4*)(err2 + (long)bp * N);
    for (int i = threadIdx.x; i < n4; i += STB) {
        az[i] = make_int4(0, 0, 0, 0);
        ez[i] = e4[i];
    }
    __syncthreads();

    long e0 = (long)k * chunk, e1 = e0 + chunk;
    if (e1 > E) e1 = E;
    long n = e1 - e0, nv = n >> 2;
    const int4*   g4p = (const int4*)(idx + (long)E + e0);  // tgt row 1: gather
    const int4*   s4p = (const int4*)(idx + e0);            // src row 0: scatter
    const float4* w4p = (const float4*)(w + e0);

    for (long v = threadIdx.x; v < nv; v += STB) {
        int4 gi = g4p[v]; int4 si = s4p[v]; float4 wv = w4p[v];
        h2 w0 = { (_Float16)wv.x, (_Float16)wv.x };
        h2 w1 = { (_Float16)wv.y, (_Float16)wv.y };
        h2 w2 = { (_Float16)wv.z, (_Float16)wv.z };
        h2 w3 = { (_Float16)wv.w, (_Float16)wv.w };
        h2 m0 = w0 * es2[gi.x];
        h2 m1 = w1 * es2[gi.y];
        h2 m2 = w2 * es2[gi.z];
        h2 m3 = w3 * es2[gi.w];
        lds_pk_add(&acc2[si.x], m0);
        lds_pk_add(&acc2[si.y], m1);
        lds_pk_add(&acc2[si.z], m2);
        lds_pk_add(&acc2[si.w], m3);
    }
    for (long e = (nv << 2) + threadIdx.x; e < n; e += STB) {
        int gi = idx[(long)E + e0 + e], si = idx[e0 + e];
        _Float16 wf = (_Float16)w[e0 + e];
        h2 wb = { wf, wf };
        lds_pk_add(&acc2[si], wb * es2[gi]);
    }
    __syncthreads();

    int4* pz = (int4*)(partial + ((long)k * 4 + bp) * N);
    for (int i = threadIdx.x; i < n4; i += STB) pz[i] = az[i];
}

// ---------------- reduce 1: pred, err, err2 ----------------
// block = 512 thr: 64 lanes (each owning 4 consecutive t via int4 loads)
// x 8 k-groups; fp32 cross-chunk accumulation; LDS tree; float4 epilogue.
__global__ __launch_bounds__(512) void reduce1_kernel(
        const h2* __restrict__ partial,
        const float* __restrict__ values,
        float* __restrict__ pred, float* __restrict__ err,
        h2* __restrict__ err2, int N, int K)
{
    __shared__ float2 sm[8][64][4];
    const int l = threadIdx.x & 63, g = threadIdx.x >> 6;
    const int bp = blockIdx.y;
    const int t = blockIdx.x * 256 + l * 4;
    float2 a0 = {0.f,0.f}, a1 = {0.f,0.f}, a2 = {0.f,0.f}, a3 = {0.f,0.f};
    const bool ok = (t + 3) < N;
    if (ok) {
        for (int kk = g; kk < K; kk += 8) {
            int4 v = *(const int4*)(partial + (long)(kk * 4 + bp) * N + t);
            h2* hp = (h2*)&v;
            a0.x += (float)hp[0].x; a0.y += (float)hp[0].y;
            a1.x += (float)hp[1].x; a1.y += (float)hp[1].y;
            a2.x += (float)hp[2].x; a2.y += (float)hp[2].y;
            a3.x += (float)hp[3].x; a3.y += (float)hp[3].y;
        }
    }
    sm[g][l][0] = a0; sm[g][l][1] = a1; sm[g][l][2] = a2; sm[g][l][3] = a3;
    __syncthreads();
    if (g == 0 && ok) {
#pragma unroll
        for (int r = 1; r < 8; ++r) {
            a0.x += sm[r][l][0].x; a0.y += sm[r][l][0].y;
            a1.x += sm[r][l][1].x; a1.y += sm[r][l][1].y;
            a2.x += sm[r][l][2].x; a2.y += sm[r][l][2].y;
            a3.x += sm[r][l][3].x; a3.y += sm[r][l][3].y;
        }
        long j0 = (long)(2 * bp) * N + t, j1 = j0 + N;
        float4 p0 = { a0.x, a1.x, a2.x, a3.x };
        float4 p1 = { a0.y, a1.y, a2.y, a3.y };
        float4 v0 = *(const float4*)(values + j0);
        float4 v1 = *(const float4*)(values + j1);
        float4 e0 = { v0.x - p0.x, v0.y - p0.y, v0.z - p0.z, v0.w - p0.w };
        float4 e1 = { v1.x - p1.x, v1.y - p1.y, v1.z - p1.z, v1.w - p1.w };
        *(float4*)(pred + j0) = p0;
        *(float4*)(pred + j1) = p1;
        *(float4*)(err + j0) = e0;
        *(float4*)(err + j1) = e1;
        h2 pk[4] = { { (_Float16)e0.x, (_Float16)e1.x },
                     { (_Float16)e0.y, (_Float16)e1.y },
                     { (_Float16)e0.z, (_Float16)e1.z },
                     { (_Float16)e0.w, (_Float16)e1.w } };
        *(int4*)(err2 + (long)bp * N + t) = *(int4*)pk;
    }
}

// ---------------- reduce 2: dx = err - (1 - tanh^2(x)) * aggr ----------------
__global__ __launch_bounds__(512) void reduce2_kernel(
        const h2* __restrict__ partial,
        const float* __restrict__ values,
        const float* __restrict__ err,
        float* __restrict__ dx, int N, int K)
{
    __shared__ float2 sm[8][64][4];
    const int l = threadIdx.x & 63, g = threadIdx.x >> 6;
    const int bp = blockIdx.y;
    const int t = blockIdx.x * 256 + l * 4;
    float2 a0 = {0.f,0.f}, a1 = {0.f,0.f}, a2 = {0.f,0.f}, a3 = {0.f,0.f};
    const bool ok = (t + 3) < N;
    if (ok) {
        for (int kk = g; kk < K; kk += 8) {
            int4 v = *(const int4*)(partial + (long)(kk * 4 + bp) * N + t);
            h2* hp = (h2*)&v;
            a0.x += (float)hp[0].x; a0.y += (float)hp[0].y;
            a1.x += (float)hp[1].x; a1.y += (float)hp[1].y;
            a2.x += (float)hp[2].x; a2.y += (float)hp[2].y;
            a3.x += (float)hp[3].x; a3.y += (float)hp[3].y;
        }
    }
    sm[g][l][0] = a0; sm[g][l][1] = a1; sm[g][l][2] = a2; sm[g][l][3] = a3;
    __syncthreads();
    if (g == 0 && ok) {
#pragma unroll
        for (int r = 1; r < 8; ++r) {
            a0.x += sm[r][l][0].x; a0.y += sm[r][l][0].y;
            a1.x += sm[r][l][1].x; a1.y += sm[r][l][1].y;
            a2.x += sm[r][l][2].x; a2.y += sm[r][l][2].y;
            a3.x += sm[r][l][3].x; a3.y += sm[r][l][3].y;
        }
        long j0 = (long)(2 * bp) * N + t, j1 = j0 + N;
        float4 g0 = { a0.x, a1.x, a2.x, a3.x };
        float4 g1 = { a0.y, a1.y, a2.y, a3.y };
        float4 v0 = *(const float4*)(values + j0);
        float4 v1 = *(const float4*)(values + j1);
        float4 e0 = *(const float4*)(err + j0);
        float4 e1 = *(const float4*)(err + j1);
        float4 d0, d1;
        float f;
        f = tanhf(v0.x); d0.x = e0.x - (1.0f - f * f) * g0.x;
        f = tanhf(v0.y); d0.y = e0.y - (1.0f - f * f) * g0.y;
        f = tanhf(v0.z); d0.z = e0.z - (1.0f - f * f) * g0.z;
        f = tanhf(v0.w); d0.w = e0.w - (1.0f - f * f) * g0.w;
        f = tanhf(v1.x); d1.x = e1.x - (1.0f - f * f) * g1.x;
        f = tanhf(v1.y); d1.y = e1.y - (1.0f - f * f) * g1.y;
        f = tanhf(v1.z); d1.z = e1.z - (1.0f - f * f) * g1.z;
        f = tanhf(v1.w); d1.w = e1.w - (1.0f - f * f) * g1.w;
        *(float4*)(dx + j0) = d0;
        *(float4*)(dx + j1) = d1;
    }
}

extern "C" void kernel_launch(void* const* d_in, const int* in_sizes, int n_in,
                              void* d_out, int out_size, void* d_ws, size_t ws_size,
                              hipStream_t stream) {
    const float* values  = (const float*)d_in[0];   // [B*N]
    const float* weights = (const float*)d_in[1];   // [E]
    const int*   edge_ix = (const int*)d_in[2];     // [2, E]

    const int BN = in_sizes[0];        // 80000
    const int E  = in_sizes[1];        // 2,000,000
    const int N  = BN / BATCH;         // 10000

    float* out  = (float*)d_out;       // [3, B*N]
    float* pred = out;
    float* err  = out + BN;
    float* dx   = out + 2 * BN;

    // workspace: err2 [4][N] h2, partial [K][4][N] h2
    auto align16 = [](size_t x) { return (x + 15) & ~(size_t)15; };
    char* ws = (char*)d_ws;
    h2* err2 = (h2*)ws;
    size_t off = align16((size_t)4 * N * sizeof(h2));
    int K = 128;
    while (K > 16 && off + (size_t)K * 4 * N * sizeof(h2) > ws_size) K >>= 1;
    h2* partial = (h2*)(ws + off);

    int chunk = (((E + K - 1) / K) + 3) & ~3;
    int Kused = (E + chunk - 1) / chunk;

    dim3 sgrid(Kused, 4);                 // 4 batch-pairs
    dim3 rgrid((N + 255) / 256, 4);       // 512-thread reduce blocks
    scatter1_kernel<<<sgrid, STB, 0, stream>>>(values, weights, edge_ix,
                                               partial, E, N, chunk);
    reduce1_kernel<<<rgrid, 512, 0, stream>>>(partial, values, pred, err,
                                              err2, N, Kused);
    scatter2_kernel<<<sgrid, STB, 0, stream>>>(err2, weights, edge_ix,
                                               partial, E, N, chunk);
    reduce2_kernel<<<rgrid, 512, 0, stream>>>(partial, values, err, dx,
                                              N, Kused);
}